// Round 6
// baseline (434.781 us; speedup 1.0000x reference)
//
#include <hip/hip_runtime.h>

// NCC loss (win=21) on vol [B=2, C=1, X=160, Y=192, Z=160] fp32.
// GOVERNING MODEL (R1/R4/R5 counters): duration == VMEM-instr count /
// (256 CU x 2.4 GHz) -- the VMEM issue rate is ~1 wave-instr/cycle/CU
// regardless of stride/occupancy. So: every global access must be 16 B.
//   P1 k_prod_yfilt: products + y-filter (R4 geometry) with GATHER STORES:
//     4 z4-lanes shfl their packed dwords to a leader -> one dwordx4.
//     vmem/thread 148 -> 103.
//   P2 k_xz_cc: FUSED x-filter + z-filter + cc. H never exists. Per-line
//     blocks: 50 producer lanes hold fp32 x-running-sums (uint4 Fy reads,
//     leave re-read is L2-hot), hand 20-x groups to consumers via 19.2 KB
//     fp8 LDS; consumers run the proven P3 z-window/cc; partial per block.
//   P4 k_final4 sums 1536 partials. No atomics/fences anywhere (R3 lesson).
// Intermediates fp8 e4m3; I^2/J^2 carry x0.25 scale, cc_term unscales x4.

typedef unsigned char u8;
typedef float f2v __attribute__((ext_vector_type(2)));

#define B_   2
#define X_   160
#define Y_   192
#define Z_   160
#define WIN_ 21
#define HALF 10
#define YZ   (Y_ * Z_)                        // 30720
#define XYZ  (X_ * YZ)                        // 4915200
#define NTOT ((size_t)B_ * X_ * Y_ * Z_)      // 9830400 (elements == bytes in fp8)
#define SXN  (B_ * X_)                        // 320

#define YSEG1 12                              // P1: 16 y-segments of 12 (R4 best)
#define NSEG1 16

// fused x/z kernel geometry
#define XS4    40                             // x-extent per block (4 segs)
#define XG4    20                             // x-group per produce/consume phase
#define LSTR   48                             // LDS line stride (dwords): 4 | 40 | 4
#define NLINES (XG4 * 5)                      // 100 LDS lines
#define TPB_XZ 320
#define NBLK_XZ (384 * 4)                     // 1536 = (B*Y) lines x 4 x-segs
#define NUNITS (XG4 * 20)                     // 400 consume units per group

__device__ __forceinline__ uint pack4_fp8(float a, float b, float c, float d)
{
    int u = 0;
    u = __builtin_amdgcn_cvt_pk_fp8_f32(a, b, u, false);
    u = __builtin_amdgcn_cvt_pk_fp8_f32(c, d, u, true);
    return (uint)u;
}

__device__ __forceinline__ float4 unpack4_fp8(uint u)
{
    f2v lo = __builtin_amdgcn_cvt_pk_f32_fp8((int)u, false);
    f2v hi = __builtin_amdgcn_cvt_pk_f32_fp8((int)u, true);
    return make_float4(lo[0], lo[1], hi[0], hi[1]);
}

__device__ __forceinline__ void upd_add(float4& W, const float4 v)
{
    W.x += v.x; W.y += v.y; W.z += v.z; W.w += v.w;
}
__device__ __forceinline__ void upd_fma(float4& W, const float4 a, const float4 b)
{
    W.x = fmaf(a.x, b.x, W.x); W.y = fmaf(a.y, b.y, W.y);
    W.z = fmaf(a.z, b.z, W.z); W.w = fmaf(a.w, b.w, W.w);
}
__device__ __forceinline__ void upd_sub2(float4& W, const float4 e, const float4 l)
{
    W.x += e.x - l.x; W.y += e.y - l.y; W.z += e.z - l.z; W.w += e.w - l.w;
}
__device__ __forceinline__ void upd_fms(float4& W, const float4 ea, const float4 eb,
                                        const float4 la, const float4 lb)
{
    W.x = fmaf(ea.x, eb.x, fmaf(-la.x, lb.x, W.x));
    W.y = fmaf(ea.y, eb.y, fmaf(-la.y, lb.y, W.y));
    W.z = fmaf(ea.z, eb.z, fmaf(-la.z, lb.z, W.z));
    W.w = fmaf(ea.w, eb.w, fmaf(-la.w, lb.w, W.w));
}

// ---------------- P1: products + y-filter (R4 geometry) + gather stores ----------
#define GNONE 0
#define GLO   1
#define GHI   2

template<int MODE>
__device__ __forceinline__ void yfilt_run(int y0,
                                          const float* __restrict__ Ib,
                                          const float* __restrict__ Jb,
                                          u8* __restrict__ Fb, bool leader)
{
    const float4 z4 = make_float4(0.f, 0.f, 0.f, 0.f);
    float4 W0 = z4, W1 = z4, W2 = z4, W3 = z4, W4 = z4;

    // init: window sum over raw rows [y0-10, y0+9]
#pragma unroll
    for (int k = 0; k < 20; ++k) {
        int u = y0 - 10 + k;
        float4 a, b;
        if (MODE == GLO) {                     // seg 0 only: u may be < 0
            a = (u >= 0) ? *(const float4*)(Ib + (size_t)u * Z_) : z4;
            b = (u >= 0) ? *(const float4*)(Jb + (size_t)u * Z_) : z4;
        } else {
            a = *(const float4*)(Ib + (size_t)u * Z_);
            b = *(const float4*)(Jb + (size_t)u * Z_);
        }
        upd_add(W0, a);
        upd_add(W1, b);
        upd_fma(W2, a, a);
        upd_fma(W3, b, b);
        upd_fma(W4, a, b);
    }

#pragma unroll
    for (int r = 0; r < YSEG1; ++r) {
        int y  = y0 + r;
        int ye = y + HALF;
        int yl = y - HALF - 1;
        float4 ea, eb, la, lb;
        if (MODE == GHI) {                     // seg 15 only: ye may be >= Y_
            ea = (ye < Y_) ? *(const float4*)(Ib + (size_t)ye * Z_) : z4;
            eb = (ye < Y_) ? *(const float4*)(Jb + (size_t)ye * Z_) : z4;
        } else {
            ea = *(const float4*)(Ib + (size_t)ye * Z_);
            eb = *(const float4*)(Jb + (size_t)ye * Z_);
        }
        if (MODE == GLO) {                     // seg 0 only: yl may be < 0
            la = (yl >= 0) ? *(const float4*)(Ib + (size_t)yl * Z_) : z4;
            lb = (yl >= 0) ? *(const float4*)(Jb + (size_t)yl * Z_) : z4;
        } else {
            la = *(const float4*)(Ib + (size_t)yl * Z_);
            lb = *(const float4*)(Jb + (size_t)yl * Z_);
        }
        upd_sub2(W0, ea, la);
        upd_sub2(W1, eb, lb);
        upd_fms(W2, ea, ea, la, la);
        upd_fms(W3, eb, eb, lb, lb);
        upd_fms(W4, ea, eb, la, lb);

        uint pk[5];
        pk[0] = pack4_fp8(W0.x, W0.y, W0.z, W0.w);
        pk[1] = pack4_fp8(W1.x, W1.y, W1.z, W1.w);
        pk[2] = pack4_fp8(W2.x * 0.25f, W2.y * 0.25f, W2.z * 0.25f, W2.w * 0.25f);
        pk[3] = pack4_fp8(W3.x * 0.25f, W3.y * 0.25f, W3.z * 0.25f, W3.w * 0.25f);
        pk[4] = pack4_fp8(W4.x, W4.y, W4.z, W4.w);
        size_t o = (size_t)y * Z_;
        // gather 4 z4-lanes' dwords into leader lane -> one dwordx4 store.
        // zg-groups of 4 are lane-aligned (wave-start zg ≡ 0 mod 4 for all waves).
#pragma unroll
        for (int ch = 0; ch < 5; ++ch) {
            uint v0 = pk[ch];
            uint v1 = __shfl_down(v0, 1, 4);
            uint v2 = __shfl_down(v0, 2, 4);
            uint v3 = __shfl_down(v0, 3, 4);
            if (leader)
                *(uint4*)(Fb + (size_t)ch * NTOT + o) = make_uint4(v0, v1, v2, v3);
        }
    }
}

// thread = (seg, bx, z4). 800 blocks x 256 = 204800 = 40 z4 x 320 bx x 16 seg.
// seg uniform per block (12800 threads per seg, 256 | 12800).
__global__ __launch_bounds__(256) void k_prod_yfilt(
    const float* __restrict__ I, const float* __restrict__ J,
    u8* __restrict__ Fy)
{
    int t   = blockIdx.x * 256 + threadIdx.x;
    int zg  = t % 40;
    int col = t / 40;
    int bx  = col % SXN;
    int seg = col / SXN;                       // [0, 16)
    const float* Ib = I + (size_t)bx * YZ + zg * 4;
    const float* Jb = J + (size_t)bx * YZ + zg * 4;
    u8* Fb = Fy + (size_t)bx * YZ + zg * 4;
    bool leader = ((zg & 3) == 0);
    int y0 = seg * YSEG1;

    if (seg == 0)            yfilt_run<GLO>(y0, Ib, Jb, Fb, leader);
    else if (seg == 15)      yfilt_run<GHI>(y0, Ib, Jb, Fb, leader);
    else                     yfilt_run<GNONE>(y0, Ib, Jb, Fb, leader);
}

// ---------------- P2: FUSED x-filter + z-filter + cc -> per-block partial ----------
__device__ __forceinline__ float cc_term(float w0, float w1, float w2, float w3,
                                         float w4, float inv_n)
{
    float cross = fmaf(-(w0 * w1), inv_n, w4);
    float Iv    = fmaf(-(w0 * w0), inv_n, w2 * 4.0f);   // unscale I2 (x0.25 in P1)
    float Jv    = fmaf(-(w1 * w1), inv_n, w3 * 4.0f);   // unscale J2
    float denom = fmaf(Iv, Jv, 1e-5f);
    return (cross * cross) * __builtin_amdgcn_rcpf(denom);
}

__device__ __forceinline__ void acc_u4(float4* W, uint4 v)
{
    const uint d[4] = { v.x, v.y, v.z, v.w };
#pragma unroll
    for (int q = 0; q < 4; ++q) {
        float4 t = unpack4_fp8(d[q]);
        W[q].x += t.x; W[q].y += t.y; W[q].z += t.z; W[q].w += t.w;
    }
}

__device__ __forceinline__ void accdiff_u4(float4* W, uint4 e, uint4 l)
{
    const uint de[4] = { e.x, e.y, e.z, e.w };
    const uint dl[4] = { l.x, l.y, l.z, l.w };
#pragma unroll
    for (int q = 0; q < 4; ++q) {
        float4 te = unpack4_fp8(de[q]);
        float4 tl = unpack4_fp8(dl[q]);
        W[q].x += te.x - tl.x; W[q].y += te.y - tl.y;
        W[q].z += te.z - tl.z; W[q].w += te.w - tl.w;
    }
}

// z-window + cc for one (x-line, z8) unit from LDS (P3's verified pattern)
__device__ __forceinline__ float consume_unit(const uint* __restrict__ lds, int u,
                                              float inv_n)
{
    int xl = u / 20;
    int zg = u % 20;                           // z0 = 8*zg
    int ub = xl * 5 * LSTR + 4 + 2 * zg - 3;   // margins make all reads valid

    float s5[5][8];
#pragma unroll
    for (int c5 = 0; c5 < 5; ++c5) {
        int la = ub + c5 * LSTR;
        float f[32];                           // z span [z0-12, z0+19]
#pragma unroll
        for (int k = 0; k < 8; ++k) {
            float4 v = unpack4_fp8(lds[la + k]);
            f[4 * k + 0] = v.x; f[4 * k + 1] = v.y;
            f[4 * k + 2] = v.z; f[4 * k + 3] = v.w;
        }
        float s0 = 0.f;
#pragma unroll
        for (int i = 2; i <= 22; ++i) s0 += f[i];
        s5[c5][0] = s0;
#pragma unroll
        for (int r = 1; r < 8; ++r) { s0 += f[r + 22] - f[r + 1]; s5[c5][r] = s0; }
    }
    float a = 0.f;
#pragma unroll
    for (int r = 0; r < 8; ++r)
        a += cc_term(s5[0][r], s5[1][r], s5[2][r], s5[3][r], s5[4][r], inv_n);
    return a;
}

template<int SEG>
__device__ __forceinline__ void xz_body(const u8* __restrict__ Fy,
                                        double* __restrict__ part,
                                        int b, int y, int tid, int bid,
                                        uint* __restrict__ lds,
                                        float* __restrict__ wsum)
{
    constexpr int X0 = SEG * XS4;
    const float inv_n = 1.0f / 9261.0f;

    // zero the z-margins of all 100 LDS lines (dwords 0..3 and 44..47)
    for (int i = tid; i < NLINES * 8; i += TPB_XZ) {
        int ln = i >> 3, m = i & 7;
        lds[ln * LSTR + (m < 4 ? m : 40 + m)] = 0u;
    }

    const bool prod = (tid < 50);
    int c   = tid / 10;                        // channel (producers)
    int z16 = tid % 10;                        // 16-z group
    const u8* base = Fy + (size_t)c * NTOT + (size_t)b * XYZ
                   + (size_t)y * Z_ + z16 * 16;

    float4 W[4] = { make_float4(0.f,0.f,0.f,0.f), make_float4(0.f,0.f,0.f,0.f),
                    make_float4(0.f,0.f,0.f,0.f), make_float4(0.f,0.f,0.f,0.f) };
    if (prod) {
        // init: x-window sum over raw rows [X0-10, X0+9]
#pragma unroll
        for (int k = 0; k < 20; ++k) {
            const int xr = X0 - 10 + k;        // compile-time
            uint4 v = make_uint4(0u, 0u, 0u, 0u);
            if (SEG > 0 || xr >= 0)
                v = *(const uint4*)(base + (size_t)xr * YZ);
            acc_u4(W, v);
        }
    }
    __syncthreads();                           // margins ready

    float lacc = 0.f;
#pragma unroll
    for (int g = 0; g < 2; ++g) {
        if (prod) {
#pragma unroll
            for (int s = 0; s < XG4; ++s) {
                const int x = X0 + g * XG4 + s;            // compile-time
                uint4 e = make_uint4(0u, 0u, 0u, 0u), l = e;
                if (SEG < 3 || x + HALF < X_)
                    e = *(const uint4*)(base + (size_t)(x + HALF) * YZ);
                if (SEG > 0 || x - HALF - 1 >= 0)
                    l = *(const uint4*)(base + (size_t)(x - HALF - 1) * YZ);
                accdiff_u4(W, e, l);
                uint4 h;
                h.x = pack4_fp8(W[0].x, W[0].y, W[0].z, W[0].w);
                h.y = pack4_fp8(W[1].x, W[1].y, W[1].z, W[1].w);
                h.z = pack4_fp8(W[2].x, W[2].y, W[2].z, W[2].w);
                h.w = pack4_fp8(W[3].x, W[3].y, W[3].z, W[3].w);
                *(uint4*)&lds[(s * 5 + c) * LSTR + 4 + z16 * 4] = h;
            }
        }
        __syncthreads();
        lacc += consume_unit(lds, tid, inv_n);
        if (tid < NUNITS - TPB_XZ)
            lacc += consume_unit(lds, tid + TPB_XZ, inv_n);
        __syncthreads();                       // before next group overwrites
    }

#pragma unroll
    for (int off = 32; off > 0; off >>= 1) lacc += __shfl_down(lacc, off);
    if ((tid & 63) == 0) wsum[tid >> 6] = lacc;
    __syncthreads();
    if (tid == 0) {
        float sm = (wsum[0] + wsum[1]) + (wsum[2] + wsum[3]) + wsum[4];
        part[bid] = (double)sm;                // plain store; kernel boundary orders
    }
}

// 1536 blocks x 320: block = ((b,y) line, x-seg). Producers: tid<50 = (c, z16).
__global__ __launch_bounds__(TPB_XZ) void k_xz_cc(const u8* __restrict__ Fy,
                                                  double* __restrict__ part)
{
    __shared__ uint  lds[NLINES * LSTR];       // 19200 B
    __shared__ float wsum[TPB_XZ / 64];
    int tid  = threadIdx.x;
    int bid  = blockIdx.x;
    int seg  = bid / 384;
    int line = bid % 384;
    int b = line / Y_;
    int y = line % Y_;
    switch (seg) {
        case 0:  xz_body<0>(Fy, part, b, y, tid, bid, lds, wsum); break;
        case 1:  xz_body<1>(Fy, part, b, y, tid, bid, lds, wsum); break;
        case 2:  xz_body<2>(Fy, part, b, y, tid, bid, lds, wsum); break;
        default: xz_body<3>(Fy, part, b, y, tid, bid, lds, wsum); break;
    }
}

// ---------------- P4: sum 1536 partials + finalize ----------------
__global__ __launch_bounds__(256) void k_final4(const double* __restrict__ part,
                                                float* __restrict__ out)
{
    int tid = threadIdx.x;
    double s = 0.0;
#pragma unroll
    for (int k = 0; k < NBLK_XZ / 256; ++k)    // 6 each
        s += part[tid + 256 * k];
#pragma unroll
    for (int off = 32; off > 0; off >>= 1) s += __shfl_down(s, off);
    __shared__ double wsum[4];
    if ((tid & 63) == 0) wsum[tid >> 6] = s;
    __syncthreads();
    if (tid == 0) {
        double tot = (wsum[0] + wsum[1]) + (wsum[2] + wsum[3]);
        out[0] = 1.0f - (float)(tot / 9830400.0);
    }
}

extern "C" void kernel_launch(void* const* d_in, const int* in_sizes, int n_in,
                              void* d_out, int out_size, void* d_ws, size_t ws_size,
                              hipStream_t stream)
{
    const float* I = (const float*)d_in[0];
    const float* J = (const float*)d_in[1];
    float* out = (float*)d_out;

    char* ws = (char*)d_ws;
    double* part = (double*)ws;                // 1536 doubles = 12.3 KB
    u8* Fy = (u8*)(ws + 32768);                // 5 x 9.83 MB = 49.2 MB (fp8)

    k_prod_yfilt<<<dim3(800), 256, 0, stream>>>(I, J, Fy);
    k_xz_cc<<<dim3(NBLK_XZ), TPB_XZ, 0, stream>>>(Fy, part);
    k_final4<<<dim3(1), 256, 0, stream>>>(part, out);
}

// Round 7
// 176.745 us; speedup vs baseline: 2.4599x; 2.4599x over previous
//
#include <hip/hip_runtime.h>

// NCC loss (win=21) on vol [B=2, C=1, X=160, Y=192, Z=160] fp32.
// Pipeline: P1 products + y-filter -> Fy (fp8); P2 x-filter Fy -> H (fp8,
// z16/thread, all uint4 accesses); P3 z-filter from LDS + cc + per-block
// partial (uint4 staging); P4 sums partials. No atomics/fences (R3 lesson).
// No cross-lane data movement in front of VMEM (R6 lesson: shfl->store chains
// serialize). Governing model: dur ~= thread-VMEM-instrs / 0.64M/us, given
// independent-wave ILP; so shrink instr count via WIDER per-thread access.
// Intermediates fp8 e4m3; I^2/J^2 carry x0.25 scale, cc_term unscales x4.

typedef unsigned char u8;
typedef float f2v __attribute__((ext_vector_type(2)));

#define B_   2
#define X_   160
#define Y_   192
#define Z_   160
#define WIN_ 21
#define HALF 10
#define YZ   (Y_ * Z_)                        // 30720
#define XYZ  (X_ * YZ)                        // 4915200
#define NTOT ((size_t)B_ * X_ * Y_ * Z_)      // 9830400 (elements == bytes in fp8)
#define SXN  (B_ * X_)                        // 320

#define YSEG1 12                              // P1: 16 y-segments of 12 (R4 best)
#define XSEG2 20                              // P2: 8 x-segments of 20
#define NSEG2 8

// P3 geometry
#define LINES3 16                             // lines per block
#define TPB3   320                            // threads per block (5 waves)
#define SEGS3  (LINES3 * 5)                   // 80 line-channel segments
#define SEGSTR 48                             // LDS stride (dwords): 4 | 40 | 4
#define NBLK3  3840                           // (B_*X_*Y_)/LINES3

__device__ __forceinline__ uint pack4_fp8(float a, float b, float c, float d)
{
    int u = 0;
    u = __builtin_amdgcn_cvt_pk_fp8_f32(a, b, u, false);
    u = __builtin_amdgcn_cvt_pk_fp8_f32(c, d, u, true);
    return (uint)u;
}

__device__ __forceinline__ float4 unpack4_fp8(uint u)
{
    f2v lo = __builtin_amdgcn_cvt_pk_f32_fp8((int)u, false);
    f2v hi = __builtin_amdgcn_cvt_pk_f32_fp8((int)u, true);
    return make_float4(lo[0], lo[1], hi[0], hi[1]);
}

__device__ __forceinline__ void upd_add(float4& W, const float4 v)
{
    W.x += v.x; W.y += v.y; W.z += v.z; W.w += v.w;
}
__device__ __forceinline__ void upd_fma(float4& W, const float4 a, const float4 b)
{
    W.x = fmaf(a.x, b.x, W.x); W.y = fmaf(a.y, b.y, W.y);
    W.z = fmaf(a.z, b.z, W.z); W.w = fmaf(a.w, b.w, W.w);
}
__device__ __forceinline__ void upd_sub2(float4& W, const float4 e, const float4 l)
{
    W.x += e.x - l.x; W.y += e.y - l.y; W.z += e.z - l.z; W.w += e.w - l.w;
}
__device__ __forceinline__ void upd_fms(float4& W, const float4 ea, const float4 eb,
                                        const float4 la, const float4 lb)
{
    W.x = fmaf(ea.x, eb.x, fmaf(-la.x, lb.x, W.x));
    W.y = fmaf(ea.y, eb.y, fmaf(-la.y, lb.y, W.y));
    W.z = fmaf(ea.z, eb.z, fmaf(-la.z, lb.z, W.z));
    W.w = fmaf(ea.w, eb.w, fmaf(-la.w, lb.w, W.w));
}

// ---------------- P1: products + y-filter (R4-verbatim, known 46 us) ----------------
#define GNONE 0
#define GLO   1
#define GHI   2

template<int MODE>
__device__ __forceinline__ void yfilt_run(int y0,
                                          const float* __restrict__ Ib,
                                          const float* __restrict__ Jb,
                                          u8* __restrict__ Fb)
{
    const float4 z4 = make_float4(0.f, 0.f, 0.f, 0.f);
    float4 W0 = z4, W1 = z4, W2 = z4, W3 = z4, W4 = z4;

    // init: window sum over raw rows [y0-10, y0+9]
#pragma unroll
    for (int k = 0; k < 20; ++k) {
        int u = y0 - 10 + k;
        float4 a, b;
        if (MODE == GLO) {                     // seg 0 only: u may be < 0
            a = (u >= 0) ? *(const float4*)(Ib + (size_t)u * Z_) : z4;
            b = (u >= 0) ? *(const float4*)(Jb + (size_t)u * Z_) : z4;
        } else {
            a = *(const float4*)(Ib + (size_t)u * Z_);
            b = *(const float4*)(Jb + (size_t)u * Z_);
        }
        upd_add(W0, a);
        upd_add(W1, b);
        upd_fma(W2, a, a);
        upd_fma(W3, b, b);
        upd_fma(W4, a, b);
    }

#pragma unroll
    for (int r = 0; r < YSEG1; ++r) {
        int y  = y0 + r;
        int ye = y + HALF;
        int yl = y - HALF - 1;
        float4 ea, eb, la, lb;
        if (MODE == GHI) {                     // seg 15 only: ye may be >= Y_
            ea = (ye < Y_) ? *(const float4*)(Ib + (size_t)ye * Z_) : z4;
            eb = (ye < Y_) ? *(const float4*)(Jb + (size_t)ye * Z_) : z4;
        } else {
            ea = *(const float4*)(Ib + (size_t)ye * Z_);
            eb = *(const float4*)(Jb + (size_t)ye * Z_);
        }
        if (MODE == GLO) {                     // seg 0 only: yl may be < 0
            la = (yl >= 0) ? *(const float4*)(Ib + (size_t)yl * Z_) : z4;
            lb = (yl >= 0) ? *(const float4*)(Jb + (size_t)yl * Z_) : z4;
        } else {
            la = *(const float4*)(Ib + (size_t)yl * Z_);
            lb = *(const float4*)(Jb + (size_t)yl * Z_);
        }
        upd_sub2(W0, ea, la);
        upd_sub2(W1, eb, lb);
        upd_fms(W2, ea, ea, la, la);
        upd_fms(W3, eb, eb, lb, lb);
        upd_fms(W4, ea, eb, la, lb);
        size_t o = (size_t)y * Z_;
        *(uint*)(Fb + o)            = pack4_fp8(W0.x, W0.y, W0.z, W0.w);
        *(uint*)(Fb + NTOT + o)     = pack4_fp8(W1.x, W1.y, W1.z, W1.w);
        *(uint*)(Fb + 2 * NTOT + o) = pack4_fp8(W2.x * 0.25f, W2.y * 0.25f,
                                                W2.z * 0.25f, W2.w * 0.25f);
        *(uint*)(Fb + 3 * NTOT + o) = pack4_fp8(W3.x * 0.25f, W3.y * 0.25f,
                                                W3.z * 0.25f, W3.w * 0.25f);
        *(uint*)(Fb + 4 * NTOT + o) = pack4_fp8(W4.x, W4.y, W4.z, W4.w);
    }
}

// thread = (seg, bx, z4). 800 blocks x 256 = 204800 = 40 z4 x 320 bx x 16 seg.
__global__ __launch_bounds__(256) void k_prod_yfilt(
    const float* __restrict__ I, const float* __restrict__ J,
    u8* __restrict__ Fy)
{
    int t   = blockIdx.x * 256 + threadIdx.x;
    int zg  = t % 40;
    int col = t / 40;
    int bx  = col % SXN;
    int seg = col / SXN;                       // [0, 16)
    const float* Ib = I + (size_t)bx * YZ + zg * 4;
    const float* Jb = J + (size_t)bx * YZ + zg * 4;
    u8* Fb = Fy + (size_t)bx * YZ + zg * 4;
    int y0 = seg * YSEG1;

    if (seg == 0)            yfilt_run<GLO>(y0, Ib, Jb, Fb);
    else if (seg == 15)      yfilt_run<GHI>(y0, Ib, Jb, Fb);
    else                     yfilt_run<GNONE>(y0, Ib, Jb, Fb);
}

// ---------------- P2: x-filter Fy -> H, z16/thread, all-uint4 ring ----------------
#define XLO  0
#define XMID 1
#define XHI  2

__device__ __forceinline__ void acc_u4(float4* W, uint4 v)
{
    const uint d[4] = { v.x, v.y, v.z, v.w };
#pragma unroll
    for (int q = 0; q < 4; ++q) {
        float4 t = unpack4_fp8(d[q]);
        W[q].x += t.x; W[q].y += t.y; W[q].z += t.z; W[q].w += t.w;
    }
}

__device__ __forceinline__ void accdiff_u4(float4* W, uint4 e, uint4 l)
{
    const uint de[4] = { e.x, e.y, e.z, e.w };
    const uint dl[4] = { l.x, l.y, l.z, l.w };
#pragma unroll
    for (int q = 0; q < 4; ++q) {
        float4 te = unpack4_fp8(de[q]);
        float4 tl = unpack4_fp8(dl[q]);
        W[q].x += te.x - tl.x; W[q].y += te.y - tl.y;
        W[q].z += te.z - tl.z; W[q].w += te.w - tl.w;
    }
}

template<int MODE>
__device__ __forceinline__ void xseg16_run(int X0, const u8* __restrict__ Fb,
                                           u8* __restrict__ Hb)
{
    const uint4 zz = make_uint4(0u, 0u, 0u, 0u);
    uint4 ring[WIN_];
    float4 W[4] = { make_float4(0.f,0.f,0.f,0.f), make_float4(0.f,0.f,0.f,0.f),
                    make_float4(0.f,0.f,0.f,0.f), make_float4(0.f,0.f,0.f,0.f) };

#pragma unroll
    for (int k = 0; k < WIN_; ++k) {           // preload raw x-rows [X0-11, X0+9]
        int r = X0 - 11 + k;                   // r <= 149 < X_ always
        uint4 v;
        if (MODE == XLO) v = (r >= 0) ? *(const uint4*)(Fb + (size_t)r * YZ) : zz;
        else             v = *(const uint4*)(Fb + (size_t)r * YZ);
        ring[k] = v;
        acc_u4(W, v);
    }

#pragma unroll
    for (int i = 0; i < XSEG2; ++i) {          // 20 <= 21: static ring indices
        int x  = X0 + i;
        int xe = x + HALF;
        uint4 e;
        if (MODE == XHI) e = (xe < X_) ? *(const uint4*)(Fb + (size_t)xe * YZ) : zz;
        else             e = *(const uint4*)(Fb + (size_t)xe * YZ);
        accdiff_u4(W, e, ring[i]);             // leaving raw row x-11
        ring[i] = e;
        uint4 h;
        h.x = pack4_fp8(W[0].x, W[0].y, W[0].z, W[0].w);
        h.y = pack4_fp8(W[1].x, W[1].y, W[1].z, W[1].w);
        h.z = pack4_fp8(W[2].x, W[2].y, W[2].z, W[2].w);
        h.w = pack4_fp8(W[3].x, W[3].y, W[3].z, W[3].w);
        *(uint4*)(Hb + (size_t)x * YZ) = h;
    }
}

// 600 blocks x 256 = 153600 threads = 10 z16 x 192 y x 5 c x 2 b x 8 seg.
__global__ __launch_bounds__(256) void k_xfilt16(const u8* __restrict__ Fy,
                                                 u8* __restrict__ H)
{
    int t    = blockIdx.x * 256 + threadIdx.x; // [0, 153600)
    int z16  = t % 10;
    int y    = (t / 10) % Y_;
    int rest = t / (10 * Y_);                  // [0, 80)
    int c    = rest % 5;
    int bs   = rest / 5;                       // [0, 16)
    int b    = bs & 1;
    int seg  = bs >> 1;                        // [0, 8)
    size_t off = (size_t)c * NTOT + (size_t)b * XYZ
               + (size_t)y * Z_ + (size_t)z16 * 16;
    const u8* Fb = Fy + off;
    u8* Hb = H + off;
    int X0 = seg * XSEG2;

    if (seg == 0)                xseg16_run<XLO>(X0, Fb, Hb);
    else if (seg == NSEG2 - 1)   xseg16_run<XHI>(X0, Fb, Hb);
    else                         xseg16_run<XMID>(X0, Fb, Hb);
}

// ---------------- P3: LDS-staged z-filter + cc + per-block partial store ------------
__device__ __forceinline__ float cc_term(float w0, float w1, float w2, float w3,
                                         float w4, float inv_n)
{
    float cross = fmaf(-(w0 * w1), inv_n, w4);
    float Iv    = fmaf(-(w0 * w0), inv_n, w2 * 4.0f);   // unscale I2 (x0.25 in P1)
    float Jv    = fmaf(-(w1 * w1), inv_n, w3 * 4.0f);   // unscale J2
    float denom = fmaf(Iv, Jv, 1e-5f);
    return (cross * cross) * __builtin_amdgcn_rcpf(denom);
}

// NBLK3=3840 blocks x TPB3=320: block stages LINES3=16 lines x 5 ch into LDS
// via uint4 (10 lanes x 16B per 160-B segment), thread = (line, zg) computes
// 8 z-outputs from LDS, block-reduces, plain-stores one double to part[bid].
__global__ __launch_bounds__(TPB3) void k_zfilt_cc(const u8* __restrict__ H,
                                                   double* __restrict__ part)
{
    const float inv_n = 1.0f / 9261.0f;        // 21^3
    __shared__ uint lds[SEGS3 * SEGSTR];       // 80 * 48 * 4 = 15360 B
    int tid = threadIdx.x;
    int L0  = blockIdx.x * LINES3;             // first global line of this block

    // zero margins: dwords 0..3 and 44..47 of each segment (80*8 = 640 slots)
#pragma unroll
    for (int it = 0; it < 2; ++it) {
        int i  = tid + it * TPB3;              // [0, 640)
        int ln = i >> 3, m = i & 7;
        lds[ln * SEGSTR + (m < 4 ? m : 40 + m)] = 0u;
    }

    // uint4 stage: 800 uint4 per block; lanes q=0..9 cover one 160-B segment
    int q  = tid % 10;
    int sB = tid / 10;                         // [0, 32)
#pragma unroll
    for (int it = 0; it < 3; ++it) {
        int s = sB + 32 * it;                  // [0, 96)
        if (it < 2 || s < SEGS3) {
            int line = s / 5;
            int c    = s % 5;
            uint4 v = *(const uint4*)(H + (size_t)(L0 + line) * Z_
                                        + (size_t)c * NTOT + (size_t)q * 16);
            *(uint4*)&lds[s * SEGSTR + 4 + 4 * q] = v;
        }
    }
    __syncthreads();

    // compute: thread = (line, zg), 8 z outputs, window from LDS (no guards)
    int line = tid / 20;
    int zg   = tid % 20;                       // z0 = 8*zg
    int u0   = 2 * zg - 3;                     // first dword of the 8-dword window

    float s5[5][8];
#pragma unroll
    for (int c = 0; c < 5; ++c) {
        int la = (line * 5 + c) * SEGSTR + 4 + u0;   // margins make all reads valid
        float f[32];                           // z span [z0-12, z0+19]
#pragma unroll
        for (int k = 0; k < 8; ++k) {
            float4 v = unpack4_fp8(lds[la + k]);
            f[4 * k + 0] = v.x; f[4 * k + 1] = v.y;
            f[4 * k + 2] = v.z; f[4 * k + 3] = v.w;
        }
        float s0 = 0.f;
#pragma unroll
        for (int i = 2; i <= 22; ++i) s0 += f[i];   // window at z0: f[2..22]
        s5[c][0] = s0;
#pragma unroll
        for (int r = 1; r < 8; ++r) { s0 += f[r + 22] - f[r + 1]; s5[c][r] = s0; }
    }

    float lacc = 0.f;
#pragma unroll
    for (int r = 0; r < 8; ++r)
        lacc += cc_term(s5[0][r], s5[1][r], s5[2][r], s5[3][r], s5[4][r], inv_n);

#pragma unroll
    for (int off = 32; off > 0; off >>= 1) lacc += __shfl_down(lacc, off);
    __shared__ float wsum[TPB3 / 64];
    if ((tid & 63) == 0) wsum[tid >> 6] = lacc;
    __syncthreads();
    if (tid == 0) {
        float sm = 0.f;
#pragma unroll
        for (int w = 0; w < TPB3 / 64; ++w) sm += wsum[w];
        part[blockIdx.x] = (double)sm;         // plain store; kernel boundary orders it
    }
}

// ---------------- P4: sum 3840 partials + finalize ----------------
__global__ __launch_bounds__(256) void k_final4(const double* __restrict__ part,
                                                float* __restrict__ out)
{
    int tid = threadIdx.x;
    double s = 0.0;
#pragma unroll
    for (int k = 0; k < NBLK3 / 256; ++k)      // 15 each
        s += part[tid + 256 * k];
#pragma unroll
    for (int off = 32; off > 0; off >>= 1) s += __shfl_down(s, off);
    __shared__ double wsum[4];
    if ((tid & 63) == 0) wsum[tid >> 6] = s;
    __syncthreads();
    if (tid == 0) {
        double tot = (wsum[0] + wsum[1]) + (wsum[2] + wsum[3]);
        out[0] = 1.0f - (float)(tot / 9830400.0);
    }
}

extern "C" void kernel_launch(void* const* d_in, const int* in_sizes, int n_in,
                              void* d_out, int out_size, void* d_ws, size_t ws_size,
                              hipStream_t stream)
{
    const float* I = (const float*)d_in[0];
    const float* J = (const float*)d_in[1];
    float* out = (float*)d_out;

    char* ws = (char*)d_ws;
    double* part = (double*)ws;                // 3840 doubles = 30 KB
    u8* Fy = (u8*)(ws + 32768);                // 5 x 9.83 MB = 49.2 MB (fp8)
    u8* H  = Fy + 5 * NTOT;                    // 49.2 MB

    k_prod_yfilt<<<dim3(800), 256, 0, stream>>>(I, J, Fy);
    k_xfilt16<<<dim3(600), 256, 0, stream>>>(Fy, H);
    k_zfilt_cc<<<dim3(NBLK3), TPB3, 0, stream>>>(H, part);
    k_final4<<<dim3(1), 256, 0, stream>>>(part, out);
}

// Round 8
// 157.227 us; speedup vs baseline: 2.7653x; 1.1241x over previous
//
#include <hip/hip_runtime.h>

// NCC loss (win=21) on vol [B=2, C=1, X=160, Y=192, Z=160] fp32.
// P1: products + y-filter -> Fy (fp8, R4-verbatim, measured ~45 us).
// P2 k_fused_xz: x-filter + z-filter + cc FUSED; H is never materialized
// (removes 49.2 MB store + 49.2 MB re-load + LDS restage ~ 117 us of R4).
//   Structure (fixing R6's mistake): ALL 200 producer threads own a private
//   register x-ring (thread = (ch, z4), 61 dword loads -- P2's proven shape);
//   per 20-x group they dump packed fp8 x-sums into LDS, then all 256 threads
//   bulk-consume (R6's correctness-proven consume_unit: z-window + cc).
//   Only 4 barriers per block. Per-block partial double, no atomics (R3).
// P4 sums 1536 partials. fp8 e4m3 intermediates; I^2/J^2 carry x0.25 scale,
// cc_term unscales x4.

typedef unsigned char u8;
typedef float f2v __attribute__((ext_vector_type(2)));

#define B_   2
#define X_   160
#define Y_   192
#define Z_   160
#define WIN_ 21
#define HALF 10
#define YZ   (Y_ * Z_)                        // 30720
#define XYZ  (X_ * YZ)                        // 4915200
#define NTOT ((size_t)B_ * X_ * Y_ * Z_)      // 9830400 (elements == bytes in fp8)
#define SXN  (B_ * X_)                        // 320

#define YSEG1 12                              // P1: 16 y-segments of 12 (R4 best)

// fused kernel geometry
#define XSEG   40                             // x-extent per block (4 segs)
#define XGRP   20                             // x-group per produce/consume phase
#define LSTR   48                             // LDS line stride (dwords): 4 | 40 | 4
#define NLINES (XGRP * 5)                     // 100 LDS lines
#define TPB_F  256
#define NBLK_F (384 * 4)                      // 1536 = (B*Y) lines x 4 x-segs
#define NUNITS (XGRP * 20)                    // 400 consume units per group

__device__ __forceinline__ uint pack4_fp8(float a, float b, float c, float d)
{
    int u = 0;
    u = __builtin_amdgcn_cvt_pk_fp8_f32(a, b, u, false);
    u = __builtin_amdgcn_cvt_pk_fp8_f32(c, d, u, true);
    return (uint)u;
}

__device__ __forceinline__ float4 unpack4_fp8(uint u)
{
    f2v lo = __builtin_amdgcn_cvt_pk_f32_fp8((int)u, false);
    f2v hi = __builtin_amdgcn_cvt_pk_f32_fp8((int)u, true);
    return make_float4(lo[0], lo[1], hi[0], hi[1]);
}

__device__ __forceinline__ void upd_add(float4& W, const float4 v)
{
    W.x += v.x; W.y += v.y; W.z += v.z; W.w += v.w;
}
__device__ __forceinline__ void upd_fma(float4& W, const float4 a, const float4 b)
{
    W.x = fmaf(a.x, b.x, W.x); W.y = fmaf(a.y, b.y, W.y);
    W.z = fmaf(a.z, b.z, W.z); W.w = fmaf(a.w, b.w, W.w);
}
__device__ __forceinline__ void upd_sub2(float4& W, const float4 e, const float4 l)
{
    W.x += e.x - l.x; W.y += e.y - l.y; W.z += e.z - l.z; W.w += e.w - l.w;
}
__device__ __forceinline__ void upd_fms(float4& W, const float4 ea, const float4 eb,
                                        const float4 la, const float4 lb)
{
    W.x = fmaf(ea.x, eb.x, fmaf(-la.x, lb.x, W.x));
    W.y = fmaf(ea.y, eb.y, fmaf(-la.y, lb.y, W.y));
    W.z = fmaf(ea.z, eb.z, fmaf(-la.z, lb.z, W.z));
    W.w = fmaf(ea.w, eb.w, fmaf(-la.w, lb.w, W.w));
}

// ---------------- P1: products + y-filter (R4-verbatim, known ~45 us) ----------------
#define GNONE 0
#define GLO   1
#define GHI   2

template<int MODE>
__device__ __forceinline__ void yfilt_run(int y0,
                                          const float* __restrict__ Ib,
                                          const float* __restrict__ Jb,
                                          u8* __restrict__ Fb)
{
    const float4 z4 = make_float4(0.f, 0.f, 0.f, 0.f);
    float4 W0 = z4, W1 = z4, W2 = z4, W3 = z4, W4 = z4;

    // init: window sum over raw rows [y0-10, y0+9]
#pragma unroll
    for (int k = 0; k < 20; ++k) {
        int u = y0 - 10 + k;
        float4 a, b;
        if (MODE == GLO) {                     // seg 0 only: u may be < 0
            a = (u >= 0) ? *(const float4*)(Ib + (size_t)u * Z_) : z4;
            b = (u >= 0) ? *(const float4*)(Jb + (size_t)u * Z_) : z4;
        } else {
            a = *(const float4*)(Ib + (size_t)u * Z_);
            b = *(const float4*)(Jb + (size_t)u * Z_);
        }
        upd_add(W0, a);
        upd_add(W1, b);
        upd_fma(W2, a, a);
        upd_fma(W3, b, b);
        upd_fma(W4, a, b);
    }

#pragma unroll
    for (int r = 0; r < YSEG1; ++r) {
        int y  = y0 + r;
        int ye = y + HALF;
        int yl = y - HALF - 1;
        float4 ea, eb, la, lb;
        if (MODE == GHI) {                     // seg 15 only: ye may be >= Y_
            ea = (ye < Y_) ? *(const float4*)(Ib + (size_t)ye * Z_) : z4;
            eb = (ye < Y_) ? *(const float4*)(Jb + (size_t)ye * Z_) : z4;
        } else {
            ea = *(const float4*)(Ib + (size_t)ye * Z_);
            eb = *(const float4*)(Jb + (size_t)ye * Z_);
        }
        if (MODE == GLO) {                     // seg 0 only: yl may be < 0
            la = (yl >= 0) ? *(const float4*)(Ib + (size_t)yl * Z_) : z4;
            lb = (yl >= 0) ? *(const float4*)(Jb + (size_t)yl * Z_) : z4;
        } else {
            la = *(const float4*)(Ib + (size_t)yl * Z_);
            lb = *(const float4*)(Jb + (size_t)yl * Z_);
        }
        upd_sub2(W0, ea, la);
        upd_sub2(W1, eb, lb);
        upd_fms(W2, ea, ea, la, la);
        upd_fms(W3, eb, eb, lb, lb);
        upd_fms(W4, ea, eb, la, lb);
        size_t o = (size_t)y * Z_;
        *(uint*)(Fb + o)            = pack4_fp8(W0.x, W0.y, W0.z, W0.w);
        *(uint*)(Fb + NTOT + o)     = pack4_fp8(W1.x, W1.y, W1.z, W1.w);
        *(uint*)(Fb + 2 * NTOT + o) = pack4_fp8(W2.x * 0.25f, W2.y * 0.25f,
                                                W2.z * 0.25f, W2.w * 0.25f);
        *(uint*)(Fb + 3 * NTOT + o) = pack4_fp8(W3.x * 0.25f, W3.y * 0.25f,
                                                W3.z * 0.25f, W3.w * 0.25f);
        *(uint*)(Fb + 4 * NTOT + o) = pack4_fp8(W4.x, W4.y, W4.z, W4.w);
    }
}

// thread = (seg, bx, z4). 800 blocks x 256 = 204800 = 40 z4 x 320 bx x 16 seg.
__global__ __launch_bounds__(256) void k_prod_yfilt(
    const float* __restrict__ I, const float* __restrict__ J,
    u8* __restrict__ Fy)
{
    int t   = blockIdx.x * 256 + threadIdx.x;
    int zg  = t % 40;
    int col = t / 40;
    int bx  = col % SXN;
    int seg = col / SXN;                       // [0, 16)
    const float* Ib = I + (size_t)bx * YZ + zg * 4;
    const float* Jb = J + (size_t)bx * YZ + zg * 4;
    u8* Fb = Fy + (size_t)bx * YZ + zg * 4;
    int y0 = seg * YSEG1;

    if (seg == 0)            yfilt_run<GLO>(y0, Ib, Jb, Fb);
    else if (seg == 15)      yfilt_run<GHI>(y0, Ib, Jb, Fb);
    else                     yfilt_run<GNONE>(y0, Ib, Jb, Fb);
}

// ---------------- P2: FUSED x-filter + z-filter + cc ----------------
__device__ __forceinline__ float cc_term(float w0, float w1, float w2, float w3,
                                         float w4, float inv_n)
{
    float cross = fmaf(-(w0 * w1), inv_n, w4);
    float Iv    = fmaf(-(w0 * w0), inv_n, w2 * 4.0f);   // unscale I2 (x0.25 in P1)
    float Jv    = fmaf(-(w1 * w1), inv_n, w3 * 4.0f);   // unscale J2
    float denom = fmaf(Iv, Jv, 1e-5f);
    return (cross * cross) * __builtin_amdgcn_rcpf(denom);
}

// z-window + cc for one (x-line, z8) unit from LDS (R6's correctness-proven code)
__device__ __forceinline__ float consume_unit(const uint* __restrict__ lds, int u,
                                              float inv_n)
{
    int xl = u / 20;
    int zg = u % 20;                           // z0 = 8*zg
    int ub = xl * 5 * LSTR + 4 + 2 * zg - 3;   // margins make all reads valid

    float s5[5][8];
#pragma unroll
    for (int c5 = 0; c5 < 5; ++c5) {
        int la = ub + c5 * LSTR;
        float f[32];                           // z span [z0-12, z0+19]
#pragma unroll
        for (int k = 0; k < 8; ++k) {
            float4 v = unpack4_fp8(lds[la + k]);
            f[4 * k + 0] = v.x; f[4 * k + 1] = v.y;
            f[4 * k + 2] = v.z; f[4 * k + 3] = v.w;
        }
        float s0 = 0.f;
#pragma unroll
        for (int i = 2; i <= 22; ++i) s0 += f[i];
        s5[c5][0] = s0;
#pragma unroll
        for (int r = 1; r < 8; ++r) { s0 += f[r + 22] - f[r + 1]; s5[c5][r] = s0; }
    }
    float a = 0.f;
#pragma unroll
    for (int r = 0; r < 8; ++r)
        a += cc_term(s5[0][r], s5[1][r], s5[2][r], s5[3][r], s5[4][r], inv_n);
    return a;
}

template<int SEG>
__device__ __forceinline__ void fused_body(const u8* __restrict__ Fy,
                                           double* __restrict__ part,
                                           int b, int y, int tid, int bid,
                                           uint* __restrict__ lds,
                                           float* __restrict__ wsum)
{
    constexpr int X0 = SEG * XSEG;
    const float inv_n = 1.0f / 9261.0f;

    // zero the z-margins of all 100 LDS lines (dwords 0..3 and 44..47)
#pragma unroll
    for (int it = 0; it < 4; ++it) {
        int i = tid + it * TPB_F;
        if (i < NLINES * 8) {
            int ln = i >> 3, m = i & 7;
            lds[ln * LSTR + (m < 4 ? m : 40 + m)] = 0u;
        }
    }

    // producers: 200 threads = (ch, z4), each with a private 21-deep x-ring
    const bool prod = (tid < 200);
    int c  = tid / 40;                         // [0,5)
    int z4 = tid % 40;
    const u8* base = Fy + (size_t)c * NTOT + (size_t)b * XYZ
                   + (size_t)y * Z_ + (size_t)z4 * 4;

    uint ring[WIN_];
    float4 W = make_float4(0.f, 0.f, 0.f, 0.f);
    if (prod) {
        // preload raw x-rows [X0-11, X0+9] (first step adds X0+10, drops X0-11)
#pragma unroll
        for (int k = 0; k < WIN_; ++k) {
            const int r = X0 - 11 + k;         // SEG>0: r >= 29, no guard
            uint v = 0u;
            if (SEG > 0 || r >= 0) v = *(const uint*)(base + (size_t)r * YZ);
            ring[k] = v;
            float4 t = unpack4_fp8(v);
            W.x += t.x; W.y += t.y; W.z += t.z; W.w += t.w;
        }
    }
    __syncthreads();                           // margins ready

    float lacc = 0.f;
#pragma unroll
    for (int g = 0; g < 2; ++g) {
        if (prod) {
#pragma unroll
            for (int s = 0; s < XGRP; ++s) {
                const int step = g * XGRP + s; // compile-time
                const int x    = X0 + step;
                const int ri   = step % WIN_;  // compile-time ring slot
                uint e = 0u;
                if (SEG < 3 || x + HALF < X_)  // static per iteration
                    e = *(const uint*)(base + (size_t)(x + HALF) * YZ);
                float4 te = unpack4_fp8(e);
                float4 tl = unpack4_fp8(ring[ri]);   // leaving raw row x-11
                W.x += te.x - tl.x; W.y += te.y - tl.y;
                W.z += te.z - tl.z; W.w += te.w - tl.w;
                ring[ri] = e;
                lds[(s * 5 + c) * LSTR + 4 + z4] = pack4_fp8(W.x, W.y, W.z, W.w);
            }
        }
        __syncthreads();                       // group's 20 x-slices ready
        lacc += consume_unit(lds, tid, inv_n);
        if (tid < NUNITS - TPB_F)              // units 256..399
            lacc += consume_unit(lds, tid + TPB_F, inv_n);
        __syncthreads();                       // before next group overwrites
    }

#pragma unroll
    for (int off = 32; off > 0; off >>= 1) lacc += __shfl_down(lacc, off);
    if ((tid & 63) == 0) wsum[tid >> 6] = lacc;
    __syncthreads();
    if (tid == 0)
        part[bid] = (double)((wsum[0] + wsum[1]) + (wsum[2] + wsum[3]));
}

// 1536 blocks x 256: block = ((b,y) line, x-seg).
__global__ __launch_bounds__(TPB_F) void k_fused_xz(const u8* __restrict__ Fy,
                                                    double* __restrict__ part)
{
    __shared__ uint  lds[NLINES * LSTR];       // 19200 B
    __shared__ float wsum[TPB_F / 64];
    int tid  = threadIdx.x;
    int bid  = blockIdx.x;
    int seg  = bid / 384;
    int line = bid % 384;
    int b = line / Y_;
    int y = line % Y_;
    switch (seg) {
        case 0:  fused_body<0>(Fy, part, b, y, tid, bid, lds, wsum); break;
        case 1:  fused_body<1>(Fy, part, b, y, tid, bid, lds, wsum); break;
        case 2:  fused_body<2>(Fy, part, b, y, tid, bid, lds, wsum); break;
        default: fused_body<3>(Fy, part, b, y, tid, bid, lds, wsum); break;
    }
}

// ---------------- P4: sum 1536 partials + finalize ----------------
__global__ __launch_bounds__(256) void k_final4(const double* __restrict__ part,
                                                float* __restrict__ out)
{
    int tid = threadIdx.x;
    double s = 0.0;
#pragma unroll
    for (int k = 0; k < NBLK_F / 256; ++k)     // 6 each
        s += part[tid + 256 * k];
#pragma unroll
    for (int off = 32; off > 0; off >>= 1) s += __shfl_down(s, off);
    __shared__ double wsum[4];
    if ((tid & 63) == 0) wsum[tid >> 6] = s;
    __syncthreads();
    if (tid == 0) {
        double tot = (wsum[0] + wsum[1]) + (wsum[2] + wsum[3]);
        out[0] = 1.0f - (float)(tot / 9830400.0);
    }
}

extern "C" void kernel_launch(void* const* d_in, const int* in_sizes, int n_in,
                              void* d_out, int out_size, void* d_ws, size_t ws_size,
                              hipStream_t stream)
{
    const float* I = (const float*)d_in[0];
    const float* J = (const float*)d_in[1];
    float* out = (float*)d_out;

    char* ws = (char*)d_ws;
    double* part = (double*)ws;                // 1536 doubles
    u8* Fy = (u8*)(ws + 32768);                // 5 x 9.83 MB = 49.2 MB (fp8)

    k_prod_yfilt<<<dim3(800), 256, 0, stream>>>(I, J, Fy);
    k_fused_xz<<<dim3(NBLK_F), TPB_F, 0, stream>>>(Fy, part);
    k_final4<<<dim3(1), 256, 0, stream>>>(part, out);
}